// Round 1
// baseline (291.563 us; speedup 1.0000x reference)
//
#include <hip/hip_runtime.h>
#include <cstdint>

typedef unsigned short u16;
typedef __bf16 bf16x8 __attribute__((ext_vector_type(8)));
typedef float f32x4 __attribute__((ext_vector_type(4)));

#define M_DIM 8192
#define N_DIM 1024
#define I_DIM 1024
#define DEGP1 9
#define K_DIM (I_DIM * DEGP1)   /* 9216 */
#define BM 128
#define BN 128
#define BK 64

__device__ __forceinline__ u16 f2bf(float f) {
    union { float f; uint32_t u; } v; v.f = f;
    return (u16)((v.u + 0x7FFFu + ((v.u >> 16) & 1u)) >> 16);
}

// CK-style global->LDS direct load, 16B per lane. LDS dest must be linear
// (wave-uniform base + lane*16); swizzling is done on the GLOBAL source side.
__device__ __forceinline__ void gload_lds16(const u16* g, u16* l) {
    auto lp = reinterpret_cast<__attribute__((address_space(3))) uint32_t*>(
        reinterpret_cast<uintptr_t>(l));
    __builtin_amdgcn_global_load_lds(reinterpret_cast<const uint32_t*>(g), lp, 16, 0, 0);
}

// ---------------------------------------------------------------------------
// Kernel 1: Bt[o][i*9+d] = (bf16)coeffs[i][o][d]
// ---------------------------------------------------------------------------
__global__ void aw_transform(const float* __restrict__ coeffs, u16* __restrict__ Bt)
{
    int io = blockIdx.x * 256 + threadIdx.x;   // 0 .. 1024*1024-1
    int i = io & (I_DIM - 1);
    int o = io >> 10;
    const float* src = coeffs + ((size_t)i * N_DIM + o) * DEGP1;
    u16* dst = Bt + (size_t)o * K_DIM + (size_t)i * DEGP1;
#pragma unroll
    for (int d = 0; d < DEGP1; ++d) dst[d] = f2bf(src[d]);
}

// ---------------------------------------------------------------------------
// Kernel 2: A[rb][i*9+d] = (bf16) basis_d(x[row0+rb][i]) ; 8 i's per thread
// ---------------------------------------------------------------------------
__global__ void aw_basis(const float* __restrict__ x,
                         const float* __restrict__ pa, const float* __restrict__ pb,
                         const float* __restrict__ pc, const float* __restrict__ pd,
                         const float* __restrict__ pq,
                         u16* __restrict__ A, int row0)
{
    int t  = blockIdx.x * 256 + threadIdx.x;
    int rb = t >> 7;            // local row in chunk
    int g  = t & 127;
    int i0 = g << 3;
    int b  = row0 + rb;

    float a = *pa, bb = *pb, c = *pc, d = *pd, q = *pq;
    float ab = a * bb, cd = c * d, abcd = ab * cd;

    float qp[17];
    qp[0] = 1.f;
#pragma unroll
    for (int k = 1; k <= 16; ++k) qp[k] = qp[k - 1] * q;

    float den1 = 1.f + abcd * q * q;
    float c1x = 2.f * (1.f + ab * q) / den1;
    float c1c = -(a + bb) * (1.f + cd * q) / den1;

    float An[DEGP1], Cn[DEGP1], Sn[DEGP1];
#pragma unroll
    for (int n = 2; n <= 8; ++n) {
        float t1 = 1.f - ab * qp[n - 1];
        float t2 = 1.f - cd * qp[n - 1];
        float t3 = 1.f - abcd * qp[2 * n - 2];
        float t4 = 1.f - abcd * qp[2 * n - 1];
        float t5 = 1.f - abcd * qp[2 * n];
        An[n] = (t1 * t2 * t3) / (t4 * t5);
        Cn[n] = ((1.f - qp[n]) * t1 * t2 * t3) / (t3 * t4);
        Sn[n] = 1.f / (1.f - qp[n]);
    }

    const float4* x4 = (const float4*)(x + (size_t)b * I_DIM + i0);
    float4 v0 = x4[0], v1 = x4[1];
    float xv[8] = {v0.x, v0.y, v0.z, v0.w, v1.x, v1.y, v1.z, v1.w};

    u16 ob[72];
#pragma unroll
    for (int j = 0; j < 8; ++j) {
        float xj = xv[j];
        float p1 = c1x * xj + c1c;
        ob[j * 9 + 0] = 0x3F80;       // 1.0f
        ob[j * 9 + 1] = f2bf(p1);
        float pm2 = 1.f, pm1 = p1;
#pragma unroll
        for (int n = 2; n <= 8; ++n) {
            float pn = ((2.f * xj - An[n]) * pm1 - Cn[n] * pm2) * Sn[n];
            ob[j * 9 + n] = f2bf(pn);
            pm2 = pm1; pm1 = pn;
        }
    }

    // 72 bf16 = 144B contiguous, 16B-aligned (i0*9*2 = 144*(i0/8))
    uint4* dst = (uint4*)(A + (size_t)rb * K_DIM + (size_t)i0 * DEGP1);
    const uint4* s = (const uint4*)ob;
#pragma unroll
    for (int u = 0; u < 9; ++u) dst[u] = s[u];
}

// ---------------------------------------------------------------------------
// Kernel 3: C[row0+m][n] = sum_k A[m][k] * B[n][k]   (both [outer][K] bf16)
// m97 structure: 128x128 tile, BK=64, 4 waves (2x2) x 4x4 16x16x32 frags,
// global_load_lds w=16, T2 XOR swizzle (slot ^= row&7) via pre-swizzled source.
// ---------------------------------------------------------------------------
__global__ __launch_bounds__(256) void aw_gemm(
    const u16* __restrict__ A,   // rowBlocks*128 x K (chunk-local)
    const u16* __restrict__ B,   // 1024 x K
    float* __restrict__ C,       // 8192 x 1024
    int row0, int rowBlocks)
{
    __shared__ u16 As[BM * BK];
    __shared__ u16 Bs[BN * BK];

    // bijective XCD swizzle: each XCD gets a contiguous logical chunk
    int nwg = rowBlocks * 8;
    int bid = blockIdx.x;
    int per = nwg >> 3;
    int logical = (bid & 7) * per + (bid >> 3);
    int rowBlk = logical >> 3;   // 8 col-blocks (N=1024/BN)
    int colBlk = logical & 7;

    int lane = threadIdx.x & 63;
    int wid  = threadIdx.x >> 6;
    int wr = wid >> 1, wc = wid & 1;

    const size_t aBase = (size_t)rowBlk * BM * K_DIM;
    const size_t bBase = (size_t)colBlk * BN * K_DIM;

    f32x4 acc[4][4];
#pragma unroll
    for (int mi = 0; mi < 4; ++mi)
#pragma unroll
        for (int ni = 0; ni < 4; ++ni)
            acc[mi][ni] = (f32x4){0.f, 0.f, 0.f, 0.f};

    // staging geometry: idx = j*256+tid covers LDS bf16 [idx*8, idx*8+8)
    // r = idx/8 (tile row), sl = idx%8 (16B slot); source slot = sl ^ (r&7)
    const int sidx = threadIdx.x;

    for (int kt = 0; kt < K_DIM / BK; ++kt) {
        const int k0 = kt * BK;
#pragma unroll
        for (int j = 0; j < 4; ++j) {
            int idx = j * 256 + sidx;
            int r = idx >> 3, sl = idx & 7;
            int col = (sl ^ (r & 7)) << 3;
            gload_lds16(A + aBase + (size_t)r * K_DIM + k0 + col, &As[idx << 3]);
        }
#pragma unroll
        for (int j = 0; j < 4; ++j) {
            int idx = j * 256 + sidx;
            int r = idx >> 3, sl = idx & 7;
            int col = (sl ^ (r & 7)) << 3;
            gload_lds16(B + bBase + (size_t)r * K_DIM + k0 + col, &Bs[idx << 3]);
        }
        __syncthreads();   // drains vmcnt(0): LDS tiles complete

#pragma unroll
        for (int ks = 0; ks < 2; ++ks) {
            bf16x8 af[4], bfr[4];
#pragma unroll
            for (int mi = 0; mi < 4; ++mi) {
                int r = wr * 64 + mi * 16 + (lane & 15);
                int s = ks * 4 + (lane >> 4);
                af[mi] = *(const bf16x8*)((const char*)As + r * 128 + ((s ^ (r & 7)) << 4));
            }
#pragma unroll
            for (int ni = 0; ni < 4; ++ni) {
                int r = wc * 64 + ni * 16 + (lane & 15);
                int s = ks * 4 + (lane >> 4);
                bfr[ni] = *(const bf16x8*)((const char*)Bs + r * 128 + ((s ^ (r & 7)) << 4));
            }
#pragma unroll
            for (int mi = 0; mi < 4; ++mi)
#pragma unroll
                for (int ni = 0; ni < 4; ++ni)
                    acc[mi][ni] = __builtin_amdgcn_mfma_f32_16x16x32_bf16(
                        af[mi], bfr[ni], acc[mi][ni], 0, 0, 0);
        }
        __syncthreads();   // all reads done before next stage overwrites
    }

    // epilogue: D layout col=lane&15, row=(lane>>4)*4+j  [m89]
    int gRow = row0 + rowBlk * BM + wr * 64;
    int gCol = colBlk * BN + wc * 64;
#pragma unroll
    for (int mi = 0; mi < 4; ++mi) {
#pragma unroll
        for (int ni = 0; ni < 4; ++ni) {
            int rr = gRow + mi * 16 + ((lane >> 4) << 2);
            int cc = gCol + ni * 16 + (lane & 15);
            float* dst = C + (size_t)rr * N_DIM + cc;
#pragma unroll
            for (int j = 0; j < 4; ++j) dst[(size_t)j * N_DIM] = acc[mi][ni][j];
        }
    }
}

// ---------------------------------------------------------------------------
extern "C" void kernel_launch(void* const* d_in, const int* in_sizes, int n_in,
                              void* d_out, int out_size, void* d_ws, size_t ws_size,
                              hipStream_t stream)
{
    const float* x      = (const float*)d_in[0];
    const float* pa     = (const float*)d_in[1];
    const float* pb     = (const float*)d_in[2];
    const float* pc     = (const float*)d_in[3];
    const float* pd     = (const float*)d_in[4];
    const float* pq     = (const float*)d_in[5];
    const float* coeffs = (const float*)d_in[6];
    float* out = (float*)d_out;

    u16* Bt = (u16*)d_ws;
    const size_t btBytes = (size_t)N_DIM * K_DIM * sizeof(u16);   // 18.9 MB
    u16* Abuf = (u16*)((char*)d_ws + btBytes);
    size_t avail = ws_size > btBytes ? ws_size - btBytes : 0;

    // largest power-of-two row chunk that fits in remaining workspace
    int chunk = M_DIM;
    while (chunk > 128 && (size_t)chunk * K_DIM * sizeof(u16) > avail) chunk >>= 1;

    aw_transform<<<(I_DIM * N_DIM) / 256, 256, 0, stream>>>(coeffs, Bt);

    for (int row0 = 0; row0 < M_DIM; row0 += chunk) {
        aw_basis<<<(chunk * 128) / 256, 256, 0, stream>>>(x, pa, pb, pc, pd, pq, Abuf, row0);
        int rowBlocks = chunk / BM;
        aw_gemm<<<rowBlocks * 8, 256, 0, stream>>>(Abuf, Bt, out, row0, rowBlocks);
    }
}

// Round 2
// 213.014 us; speedup vs baseline: 1.3688x; 1.3688x over previous
//
#include <hip/hip_runtime.h>
#include <cstdint>

typedef unsigned short u16;
typedef __bf16 bf16x8 __attribute__((ext_vector_type(8)));
typedef float f32x4 __attribute__((ext_vector_type(4)));

#define M_DIM 8192
#define N_DIM 1024
#define I_DIM 1024
#define NDEG 8                    /* stored degrees d=1..8 */
#define K_DIM (I_DIM * NDEG)      /* 8192 */
#define BM 128
#define BN 128
#define BK 64

__device__ __forceinline__ u16 f2bf(float f) {
    union { float f; uint32_t u; } v; v.f = f;
    return (u16)((v.u + 0x7FFFu + ((v.u >> 16) & 1u)) >> 16);
}

__device__ __forceinline__ void gload_lds16(const u16* g, u16* l) {
    auto lp = reinterpret_cast<__attribute__((address_space(3))) uint32_t*>(
        reinterpret_cast<uintptr_t>(l));
    __builtin_amdgcn_global_load_lds(reinterpret_cast<const uint32_t*>(g), lp, 16, 0, 0);
}

// ---------------------------------------------------------------------------
// Kernel 1: LDS-transposed transform.
//   Bt[o][i*8+d'] = (bf16) coeffs[i][o][1+d'],  d'=0..7
//   bias[o]      += sum_i coeffs[i][o][0]       (exact f32, atomic)
// 32x32 (i,o) tiles; coalesced f32x4 reads, b128 LDS writes, b32 LDS reads.
// ---------------------------------------------------------------------------
__global__ __launch_bounds__(256) void aw_transform(
    const float* __restrict__ coeffs, u16* __restrict__ Bt, float* __restrict__ bias)
{
    __shared__ float lds[32][292];          // 288 f32 per i-row + 4 pad (16B-aligned rows)
    int bi = blockIdx.x >> 5, bo = blockIdx.x & 31;
    int i0 = bi * 32, o0 = bo * 32;
    int t = threadIdx.x;

    // read phase: i-row r, 8 threads/row, 9 float4 each (32 o * 9 d = 288 f32/row)
    {
        int r = t >> 3, s = t & 7;
        const float4* src = (const float4*)(coeffs + ((size_t)(i0 + r) * N_DIM + o0) * 9);
#pragma unroll
        for (int j = 0; j < 9; ++j) {
            float4 v = src[s * 9 + j];
            *(float4*)&lds[r][(s * 9 + j) * 4] = v;
        }
    }
    __syncthreads();

    // write phase: o-row c, 8 threads/row, each packs 4 i-rows x 8 degrees = 32 bf16
    {
        int c = t >> 3, s2 = t & 7;
        u16 ob[32];
#pragma unroll
        for (int rr = 0; rr < 4; ++rr)
#pragma unroll
            for (int dd = 0; dd < 8; ++dd)
                ob[rr * 8 + dd] = f2bf(lds[s2 * 4 + rr][c * 9 + 1 + dd]);
        uint4* dst = (uint4*)(Bt + (size_t)(o0 + c) * K_DIM + (size_t)i0 * 8 + s2 * 32);
        const uint4* sp = (const uint4*)ob;
#pragma unroll
        for (int u = 0; u < 4; ++u) dst[u] = sp[u];
    }

    // bias partial: d=0 column of this tile
    if (t < 32) {
        float sum = 0.f;
#pragma unroll
        for (int rr = 0; rr < 32; ++rr) sum += lds[rr][t * 9];
        atomicAdd(&bias[o0 + t], sum);
    }
}

// ---------------------------------------------------------------------------
// Kernel 2: A[rb][i*8+d'] = (bf16) basis_{1+d'}(x[row0+rb][i]) ; 8 i's/thread
// ---------------------------------------------------------------------------
__global__ void aw_basis(const float* __restrict__ x,
                         const float* __restrict__ pa, const float* __restrict__ pb,
                         const float* __restrict__ pc, const float* __restrict__ pd,
                         const float* __restrict__ pq,
                         u16* __restrict__ A, int row0)
{
    int t  = blockIdx.x * 256 + threadIdx.x;
    int rb = t >> 7;
    int g  = t & 127;
    int i0 = g << 3;
    int b  = row0 + rb;

    float a = *pa, bb = *pb, c = *pc, d = *pd, q = *pq;
    float ab = a * bb, cd = c * d, abcd = ab * cd;

    float qp[17];
    qp[0] = 1.f;
#pragma unroll
    for (int k = 1; k <= 16; ++k) qp[k] = qp[k - 1] * q;

    float den1 = 1.f + abcd * q * q;
    float c1x = 2.f * (1.f + ab * q) / den1;
    float c1c = -(a + bb) * (1.f + cd * q) / den1;

    float An[9], Cn[9], Sn[9];
#pragma unroll
    for (int n = 2; n <= 8; ++n) {
        float t1 = 1.f - ab * qp[n - 1];
        float t2 = 1.f - cd * qp[n - 1];
        float t3 = 1.f - abcd * qp[2 * n - 2];
        float t4 = 1.f - abcd * qp[2 * n - 1];
        float t5 = 1.f - abcd * qp[2 * n];
        An[n] = (t1 * t2 * t3) / (t4 * t5);
        Cn[n] = ((1.f - qp[n]) * t1 * t2 * t3) / (t3 * t4);
        Sn[n] = 1.f / (1.f - qp[n]);
    }

    const float4* x4 = (const float4*)(x + (size_t)b * I_DIM + i0);
    float4 v0 = x4[0], v1 = x4[1];
    float xv[8] = {v0.x, v0.y, v0.z, v0.w, v1.x, v1.y, v1.z, v1.w};

    u16 ob[64];
#pragma unroll
    for (int j = 0; j < 8; ++j) {
        float xj = xv[j];
        float p1 = c1x * xj + c1c;
        ob[j * 8 + 0] = f2bf(p1);
        float pm2 = 1.f, pm1 = p1;
#pragma unroll
        for (int n = 2; n <= 8; ++n) {
            float pn = ((2.f * xj - An[n]) * pm1 - Cn[n] * pm2) * Sn[n];
            ob[j * 8 + n - 1] = f2bf(pn);
            pm2 = pm1; pm1 = pn;
        }
    }

    // 64 bf16 = 128B contiguous, 16B-aligned
    uint4* dst = (uint4*)(A + (size_t)rb * K_DIM + (size_t)i0 * 8);
    const uint4* s = (const uint4*)ob;
#pragma unroll
    for (int u = 0; u < 8; ++u) dst[u] = s[u];
}

// ---------------------------------------------------------------------------
// Kernel 3: C[row0+m][n] = bias[n] + sum_k A[m][k] * B[n][k]
// m97 structure: 128x128 tile, BK=64, 4 waves (2x2) x 4x4 16x16x32 frags,
// global_load_lds w=16, T2 XOR swizzle via pre-swizzled source.
// ---------------------------------------------------------------------------
__global__ __launch_bounds__(256) void aw_gemm(
    const u16* __restrict__ A,
    const u16* __restrict__ B,
    const float* __restrict__ bias,
    float* __restrict__ C,
    int row0, int rowBlocks)
{
    __shared__ u16 As[BM * BK];
    __shared__ u16 Bs[BN * BK];

    int nwg = rowBlocks * 8;
    int bid = blockIdx.x;
    int per = nwg >> 3;
    int logical = (bid & 7) * per + (bid >> 3);
    int rowBlk = logical >> 3;
    int colBlk = logical & 7;

    int lane = threadIdx.x & 63;
    int wid  = threadIdx.x >> 6;
    int wr = wid >> 1, wc = wid & 1;

    const size_t aBase = (size_t)rowBlk * BM * K_DIM;
    const size_t bBase = (size_t)colBlk * BN * K_DIM;

    f32x4 acc[4][4];
#pragma unroll
    for (int mi = 0; mi < 4; ++mi)
#pragma unroll
        for (int ni = 0; ni < 4; ++ni)
            acc[mi][ni] = (f32x4){0.f, 0.f, 0.f, 0.f};

    const int sidx = threadIdx.x;

    for (int kt = 0; kt < K_DIM / BK; ++kt) {
        const int k0 = kt * BK;
#pragma unroll
        for (int j = 0; j < 4; ++j) {
            int idx = j * 256 + sidx;
            int r = idx >> 3, sl = idx & 7;
            int col = (sl ^ (r & 7)) << 3;
            gload_lds16(A + aBase + (size_t)r * K_DIM + k0 + col, &As[idx << 3]);
        }
#pragma unroll
        for (int j = 0; j < 4; ++j) {
            int idx = j * 256 + sidx;
            int r = idx >> 3, sl = idx & 7;
            int col = (sl ^ (r & 7)) << 3;
            gload_lds16(B + bBase + (size_t)r * K_DIM + k0 + col, &Bs[idx << 3]);
        }
        __syncthreads();

#pragma unroll
        for (int ks = 0; ks < 2; ++ks) {
            bf16x8 af[4], bfr[4];
#pragma unroll
            for (int mi = 0; mi < 4; ++mi) {
                int r = wr * 64 + mi * 16 + (lane & 15);
                int s = ks * 4 + (lane >> 4);
                af[mi] = *(const bf16x8*)((const char*)As + r * 128 + ((s ^ (r & 7)) << 4));
            }
#pragma unroll
            for (int ni = 0; ni < 4; ++ni) {
                int r = wc * 64 + ni * 16 + (lane & 15);
                int s = ks * 4 + (lane >> 4);
                bfr[ni] = *(const bf16x8*)((const char*)Bs + r * 128 + ((s ^ (r & 7)) << 4));
            }
#pragma unroll
            for (int mi = 0; mi < 4; ++mi)
#pragma unroll
                for (int ni = 0; ni < 4; ++ni)
                    acc[mi][ni] = __builtin_amdgcn_mfma_f32_16x16x32_bf16(
                        af[mi], bfr[ni], acc[mi][ni], 0, 0, 0);
        }
        __syncthreads();
    }

    int gRow = row0 + rowBlk * BM + wr * 64;
    int gCol = colBlk * BN + wc * 64;
#pragma unroll
    for (int mi = 0; mi < 4; ++mi) {
#pragma unroll
        for (int ni = 0; ni < 4; ++ni) {
            int rr = gRow + mi * 16 + ((lane >> 4) << 2);
            int cc = gCol + ni * 16 + (lane & 15);
            float bv = bias[cc];
            float* dst = C + (size_t)rr * N_DIM + cc;
#pragma unroll
            for (int j = 0; j < 4; ++j) dst[(size_t)j * N_DIM] = acc[mi][ni][j] + bv;
        }
    }
}

// ---------------------------------------------------------------------------
extern "C" void kernel_launch(void* const* d_in, const int* in_sizes, int n_in,
                              void* d_out, int out_size, void* d_ws, size_t ws_size,
                              hipStream_t stream)
{
    const float* x      = (const float*)d_in[0];
    const float* pa     = (const float*)d_in[1];
    const float* pb     = (const float*)d_in[2];
    const float* pc     = (const float*)d_in[3];
    const float* pd     = (const float*)d_in[4];
    const float* pq     = (const float*)d_in[5];
    const float* coeffs = (const float*)d_in[6];
    float* out = (float*)d_out;

    float* bias = (float*)d_ws;
    const size_t biasBytes = 4096;
    u16* Bt = (u16*)((char*)d_ws + biasBytes);
    const size_t btBytes = (size_t)N_DIM * K_DIM * sizeof(u16);   // 16.8 MB
    u16* Abuf = (u16*)((char*)d_ws + biasBytes + btBytes);
    size_t used = biasBytes + btBytes;
    size_t avail = ws_size > used ? ws_size - used : 0;

    int chunk = M_DIM;
    while (chunk > 128 && (size_t)chunk * K_DIM * sizeof(u16) > avail) chunk >>= 1;

    hipMemsetAsync(bias, 0, N_DIM * sizeof(float), stream);
    aw_transform<<<1024, 256, 0, stream>>>(coeffs, Bt, bias);

    for (int row0 = 0; row0 < M_DIM; row0 += chunk) {
        aw_basis<<<(chunk * 128) / 256, 256, 0, stream>>>(x, pa, pb, pc, pd, pq, Abuf, row0);
        int rowBlocks = chunk / BM;
        aw_gemm<<<rowBlocks * 8, 256, 0, stream>>>(Abuf, Bt, bias, out, row0, rowBlocks);
    }
}

// Round 3
// 197.387 us; speedup vs baseline: 1.4771x; 1.0792x over previous
//
#include <hip/hip_runtime.h>
#include <cstdint>

typedef unsigned short u16;
typedef __bf16 bf16x8 __attribute__((ext_vector_type(8)));
typedef float f32x4 __attribute__((ext_vector_type(4)));

#define M_DIM 8192
#define N_DIM 1024
#define I_DIM 1024
#define NDEG 8                    /* stored degrees d=1..8 */
#define K_DIM (I_DIM * NDEG)      /* 8192 */
#define BM 256
#define BN 128
#define BK 64
#define NT (K_DIM / BK)           /* 128 K-tiles */
#define A_TILE (BM * BK)          /* 16384 u16 = 32 KB */
#define B_TILE (BN * BK)          /* 8192  u16 = 16 KB */

__device__ __forceinline__ u16 f2bf(float f) {
    union { float f; uint32_t u; } v; v.f = f;
    return (u16)((v.u + 0x7FFFu + ((v.u >> 16) & 1u)) >> 16);
}

__device__ __forceinline__ void gload_lds16(const u16* g, u16* l) {
    auto lp = reinterpret_cast<__attribute__((address_space(3))) uint32_t*>(
        reinterpret_cast<uintptr_t>(l));
    __builtin_amdgcn_global_load_lds(reinterpret_cast<const uint32_t*>(g), lp, 16, 0, 0);
}

// ---------------------------------------------------------------------------
// Kernel 1: LDS-transposed transform.
//   Bt[o][i*8+d'] = (bf16) coeffs[i][o][1+d'],  d'=0..7
//   bias[o]      += sum_i coeffs[i][o][0]       (exact f32, atomic)
// ---------------------------------------------------------------------------
__global__ __launch_bounds__(256) void aw_transform(
    const float* __restrict__ coeffs, u16* __restrict__ Bt, float* __restrict__ bias)
{
    __shared__ float lds[32][292];
    int bi = blockIdx.x >> 5, bo = blockIdx.x & 31;
    int i0 = bi * 32, o0 = bo * 32;
    int t = threadIdx.x;

    {
        int r = t >> 3, s = t & 7;
        const float4* src = (const float4*)(coeffs + ((size_t)(i0 + r) * N_DIM + o0) * 9);
#pragma unroll
        for (int j = 0; j < 9; ++j) {
            float4 v = src[s * 9 + j];
            *(float4*)&lds[r][(s * 9 + j) * 4] = v;
        }
    }
    __syncthreads();

    {
        int c = t >> 3, s2 = t & 7;
        u16 ob[32];
#pragma unroll
        for (int rr = 0; rr < 4; ++rr)
#pragma unroll
            for (int dd = 0; dd < 8; ++dd)
                ob[rr * 8 + dd] = f2bf(lds[s2 * 4 + rr][c * 9 + 1 + dd]);
        uint4* dst = (uint4*)(Bt + (size_t)(o0 + c) * K_DIM + (size_t)i0 * 8 + s2 * 32);
        const uint4* sp = (const uint4*)ob;
#pragma unroll
        for (int u = 0; u < 4; ++u) dst[u] = sp[u];
    }

    if (t < 32) {
        float sum = 0.f;
#pragma unroll
        for (int rr = 0; rr < 32; ++rr) sum += lds[rr][t * 9];
        atomicAdd(&bias[o0 + t], sum);
    }
}

// ---------------------------------------------------------------------------
// Kernel 2: A[rb][i*8+d'] = (bf16) basis_{1+d'}(x[row0+rb][i]) ; 8 i's/thread
// ---------------------------------------------------------------------------
__global__ void aw_basis(const float* __restrict__ x,
                         const float* __restrict__ pa, const float* __restrict__ pb,
                         const float* __restrict__ pc, const float* __restrict__ pd,
                         const float* __restrict__ pq,
                         u16* __restrict__ A, int row0)
{
    int t  = blockIdx.x * 256 + threadIdx.x;
    int rb = t >> 7;
    int g  = t & 127;
    int i0 = g << 3;
    int b  = row0 + rb;

    float a = *pa, bb = *pb, c = *pc, d = *pd, q = *pq;
    float ab = a * bb, cd = c * d, abcd = ab * cd;

    float qp[17];
    qp[0] = 1.f;
#pragma unroll
    for (int k = 1; k <= 16; ++k) qp[k] = qp[k - 1] * q;

    float den1 = 1.f + abcd * q * q;
    float c1x = 2.f * (1.f + ab * q) / den1;
    float c1c = -(a + bb) * (1.f + cd * q) / den1;

    float An[9], Cn[9], Sn[9];
#pragma unroll
    for (int n = 2; n <= 8; ++n) {
        float t1 = 1.f - ab * qp[n - 1];
        float t2 = 1.f - cd * qp[n - 1];
        float t3 = 1.f - abcd * qp[2 * n - 2];
        float t4 = 1.f - abcd * qp[2 * n - 1];
        float t5 = 1.f - abcd * qp[2 * n];
        An[n] = (t1 * t2 * t3) / (t4 * t5);
        Cn[n] = ((1.f - qp[n]) * t1 * t2 * t3) / (t3 * t4);
        Sn[n] = 1.f / (1.f - qp[n]);
    }

    const float4* x4 = (const float4*)(x + (size_t)b * I_DIM + i0);
    float4 v0 = x4[0], v1 = x4[1];
    float xv[8] = {v0.x, v0.y, v0.z, v0.w, v1.x, v1.y, v1.z, v1.w};

    u16 ob[64];
#pragma unroll
    for (int j = 0; j < 8; ++j) {
        float xj = xv[j];
        float p1 = c1x * xj + c1c;
        ob[j * 8 + 0] = f2bf(p1);
        float pm2 = 1.f, pm1 = p1;
#pragma unroll
        for (int n = 2; n <= 8; ++n) {
            float pn = ((2.f * xj - An[n]) * pm1 - Cn[n] * pm2) * Sn[n];
            ob[j * 8 + n - 1] = f2bf(pn);
            pm2 = pm1; pm1 = pn;
        }
    }

    uint4* dst = (uint4*)(A + (size_t)rb * K_DIM + (size_t)i0 * 8);
    const uint4* s = (const uint4*)ob;
#pragma unroll
    for (int u = 0; u < 8; ++u) dst[u] = s[u];
}

// ---------------------------------------------------------------------------
// Kernel 3: deep-pipelined GEMM.  C[row0+m][n] = bias[n] + sum_k A[m][k]*B[n][k]
// BM=256 x BN=128, BK=64, 512 thr (8 waves 4Mx2N, 64x64/wave), triple-buffered
// LDS (144 KiB), counted vmcnt(12) (T4), setprio around MFMA (T5), XOR swizzle
// via pre-swizzled source (T2), bijective XCD swizzle (T1).
// ---------------------------------------------------------------------------
__global__ __launch_bounds__(512) void aw_gemm(
    const u16* __restrict__ A,
    const u16* __restrict__ B,
    const float* __restrict__ bias,
    float* __restrict__ C,
    int row0, int rowBlocks)
{
    __shared__ u16 As[3 * A_TILE];   // 96 KB
    __shared__ u16 Bs[3 * B_TILE];   // 48 KB

    // T1: bijective XCD swizzle (nwg = rowBlocks*8, multiple of 8)
    int nwg = rowBlocks * 8;
    int bid = blockIdx.x;
    int per = nwg >> 3;
    int logical = (bid & 7) * per + (bid >> 3);
    int rowBlk = logical >> 3;       // 8 col-blocks (N=1024/BN=128)
    int colBlk = logical & 7;

    const int tid  = threadIdx.x;
    const int lane = tid & 63;
    const int wid  = tid >> 6;
    const int wr = wid & 3;          // 4 M-waves
    const int wc = wid >> 2;         // 2 N-waves

    const size_t aBase = (size_t)rowBlk * BM * K_DIM;
    const size_t bBase = (size_t)colBlk * BN * K_DIM;

    f32x4 acc[4][4];
#pragma unroll
    for (int mi = 0; mi < 4; ++mi)
#pragma unroll
        for (int ni = 0; ni < 4; ++ni)
            acc[mi][ni] = (f32x4){0.f, 0.f, 0.f, 0.f};

    // stage one K-tile: A 2048x16B (4 rounds), B 1024x16B (2 rounds)
    auto stage = [&](int kt, int buf) {
        const int k0 = kt * BK;
        u16* dA = As + buf * A_TILE;
        u16* dB = Bs + buf * B_TILE;
#pragma unroll
        for (int j = 0; j < 4; ++j) {
            int idx = j * 512 + tid;
            int r = idx >> 3, sl = idx & 7;
            int col = (sl ^ (r & 7)) << 3;
            gload_lds16(A + aBase + (size_t)r * K_DIM + k0 + col, dA + (idx << 3));
        }
#pragma unroll
        for (int j = 0; j < 2; ++j) {
            int idx = j * 512 + tid;
            int r = idx >> 3, sl = idx & 7;
            int col = (sl ^ (r & 7)) << 3;
            gload_lds16(B + bBase + (size_t)r * K_DIM + k0 + col, dB + (idx << 3));
        }
    };

    // compute one K-tile from buffer `buf`: 2 phases (ks), 16 MFMA each
    auto compute = [&](int buf) {
        const char* aB = (const char*)(As + buf * A_TILE);
        const char* bB = (const char*)(Bs + buf * B_TILE);
#pragma unroll
        for (int ks = 0; ks < 2; ++ks) {
            bf16x8 af[4], bfr[4];
#pragma unroll
            for (int mi = 0; mi < 4; ++mi) {
                int r = wr * 64 + mi * 16 + (lane & 15);
                int s = ks * 4 + (lane >> 4);
                af[mi] = *(const bf16x8*)(aB + r * 128 + ((s ^ (r & 7)) << 4));
            }
#pragma unroll
            for (int ni = 0; ni < 4; ++ni) {
                int r = wc * 64 + ni * 16 + (lane & 15);
                int s = ks * 4 + (lane >> 4);
                bfr[ni] = *(const bf16x8*)(bB + r * 128 + ((s ^ (r & 7)) << 4));
            }
            __builtin_amdgcn_s_setprio(1);
#pragma unroll
            for (int mi = 0; mi < 4; ++mi)
#pragma unroll
                for (int ni = 0; ni < 4; ++ni)
                    acc[mi][ni] = __builtin_amdgcn_mfma_f32_16x16x32_bf16(
                        af[mi], bfr[ni], acc[mi][ni], 0, 0, 0);
            __builtin_amdgcn_s_setprio(0);
        }
    };

    // prologue: 2 K-tiles in flight
    stage(0, 0);
    stage(1, 1);

    for (int t = 0; t < NT; ++t) {
        // (A) all waves done reading buffer (t+2)%3 (read during tile t-1)
        __builtin_amdgcn_s_barrier();
        if (t + 2 < NT) {
            stage(t + 2, (t + 2) % 3);
            asm volatile("s_waitcnt vmcnt(12)" ::: "memory");  // stage(t) landed
        } else if (t + 1 < NT) {
            asm volatile("s_waitcnt vmcnt(6)" ::: "memory");
        } else {
            asm volatile("s_waitcnt vmcnt(0)" ::: "memory");
        }
        // (B) every wave's stage(t) writes visible
        __builtin_amdgcn_s_barrier();
        compute(t % 3);
    }

    // epilogue: D layout col=lane&15, row=(lane>>4)*4+j  [m89]
    int gRow = row0 + rowBlk * BM + wr * 64;
    int gCol = colBlk * BN + wc * 64;
#pragma unroll
    for (int mi = 0; mi < 4; ++mi) {
#pragma unroll
        for (int ni = 0; ni < 4; ++ni) {
            int rr = gRow + mi * 16 + ((lane >> 4) << 2);
            int cc = gCol + ni * 16 + (lane & 15);
            float bv = bias[cc];
            float* dst = C + (size_t)rr * N_DIM + cc;
#pragma unroll
            for (int j = 0; j < 4; ++j) dst[(size_t)j * N_DIM] = acc[mi][ni][j] + bv;
        }
    }
}

// ---------------------------------------------------------------------------
extern "C" void kernel_launch(void* const* d_in, const int* in_sizes, int n_in,
                              void* d_out, int out_size, void* d_ws, size_t ws_size,
                              hipStream_t stream)
{
    const float* x      = (const float*)d_in[0];
    const float* pa     = (const float*)d_in[1];
    const float* pb     = (const float*)d_in[2];
    const float* pc     = (const float*)d_in[3];
    const float* pd     = (const float*)d_in[4];
    const float* pq     = (const float*)d_in[5];
    const float* coeffs = (const float*)d_in[6];
    float* out = (float*)d_out;

    float* bias = (float*)d_ws;
    const size_t biasBytes = 4096;
    u16* Bt = (u16*)((char*)d_ws + biasBytes);
    const size_t btBytes = (size_t)N_DIM * K_DIM * sizeof(u16);   // 16.8 MB
    u16* Abuf = (u16*)((char*)d_ws + biasBytes + btBytes);
    size_t used = biasBytes + btBytes;
    size_t avail = ws_size > used ? ws_size - used : 0;

    int chunk = M_DIM;
    while (chunk > 256 && (size_t)chunk * K_DIM * sizeof(u16) > avail) chunk >>= 1;

    hipMemsetAsync(bias, 0, N_DIM * sizeof(float), stream);
    aw_transform<<<1024, 256, 0, stream>>>(coeffs, Bt, bias);

    for (int row0 = 0; row0 < M_DIM; row0 += chunk) {
        aw_basis<<<(chunk * 128) / 256, 256, 0, stream>>>(x, pa, pb, pc, pd, pq, Abuf, row0);
        int rowBlocks = chunk / BM;
        aw_gemm<<<rowBlocks * 8, 512, 0, stream>>>(Abuf, Bt, bias, out, row0, rowBlocks);
    }
}

// Round 4
// 190.272 us; speedup vs baseline: 1.5324x; 1.0374x over previous
//
#include <hip/hip_runtime.h>
#include <cstdint>

typedef unsigned short u16;
typedef __bf16 bf16x8 __attribute__((ext_vector_type(8)));
typedef float f32x4 __attribute__((ext_vector_type(4)));

#define M_DIM 8192
#define N_DIM 1024
#define I_DIM 1024
#define NDEG 8                    /* stored degrees d=1..8 */
#define K_DIM (I_DIM * NDEG)      /* 8192 */
#define BM 256
#define BN 128
#define BK 64
#define NT (K_DIM / BK)           /* 128 K-tiles */
#define A_TILE (BM * BK)          /* 32 KB */
#define B_TILE (BN * BK)          /* 16 KB */

__device__ __forceinline__ u16 f2bf(float f) {
    union { float f; uint32_t u; } v; v.f = f;
    return (u16)((v.u + 0x7FFFu + ((v.u >> 16) & 1u)) >> 16);
}

__device__ __forceinline__ void gload_lds16(const u16* g, u16* l) {
    auto lp = reinterpret_cast<__attribute__((address_space(3))) uint32_t*>(
        reinterpret_cast<uintptr_t>(l));
    __builtin_amdgcn_global_load_lds(reinterpret_cast<const uint32_t*>(g), lp, 16, 0, 0);
}

// ---------------------------------------------------------------------------
// Kernel 1: LDS-transposed transform.
//   Bt[o][i*8+d'] = (bf16) coeffs[i][o][1+d'],  bias[o] += sum_i coeffs[i][o][0]
// ---------------------------------------------------------------------------
__global__ __launch_bounds__(256) void aw_transform(
    const float* __restrict__ coeffs, u16* __restrict__ Bt, float* __restrict__ bias)
{
    __shared__ float lds[32][292];
    int bi = blockIdx.x >> 5, bo = blockIdx.x & 31;
    int i0 = bi * 32, o0 = bo * 32;
    int t = threadIdx.x;

    {
        int r = t >> 3, s = t & 7;
        const float4* src = (const float4*)(coeffs + ((size_t)(i0 + r) * N_DIM + o0) * 9);
#pragma unroll
        for (int j = 0; j < 9; ++j) {
            float4 v = src[s * 9 + j];
            *(float4*)&lds[r][(s * 9 + j) * 4] = v;
        }
    }
    __syncthreads();

    {
        int c = t >> 3, s2 = t & 7;
        u16 ob[32];
#pragma unroll
        for (int rr = 0; rr < 4; ++rr)
#pragma unroll
            for (int dd = 0; dd < 8; ++dd)
                ob[rr * 8 + dd] = f2bf(lds[s2 * 4 + rr][c * 9 + 1 + dd]);
        uint4* dst = (uint4*)(Bt + (size_t)(o0 + c) * K_DIM + (size_t)i0 * 8 + s2 * 32);
        const uint4* sp = (const uint4*)ob;
#pragma unroll
        for (int u = 0; u < 4; ++u) dst[u] = sp[u];
    }

    if (t < 32) {
        float sum = 0.f;
#pragma unroll
        for (int rr = 0; rr < 32; ++rr) sum += lds[rr][t * 9];
        atomicAdd(&bias[o0 + t], sum);
    }
}

// ---------------------------------------------------------------------------
// Kernel 2: A[rb][i*8+d'] = (bf16) basis_{1+d'}(x[row0+rb][i]) ; 8 i's/thread
// ---------------------------------------------------------------------------
__global__ void aw_basis(const float* __restrict__ x,
                         const float* __restrict__ pa, const float* __restrict__ pb,
                         const float* __restrict__ pc, const float* __restrict__ pd,
                         const float* __restrict__ pq,
                         u16* __restrict__ A, int row0)
{
    int t  = blockIdx.x * 256 + threadIdx.x;
    int rb = t >> 7;
    int g  = t & 127;
    int i0 = g << 3;
    int b  = row0 + rb;

    float a = *pa, bb = *pb, c = *pc, d = *pd, q = *pq;
    float ab = a * bb, cd = c * d, abcd = ab * cd;

    float qp[17];
    qp[0] = 1.f;
#pragma unroll
    for (int k = 1; k <= 16; ++k) qp[k] = qp[k - 1] * q;

    float den1 = 1.f + abcd * q * q;
    float c1x = 2.f * (1.f + ab * q) / den1;
    float c1c = -(a + bb) * (1.f + cd * q) / den1;

    float An[9], Cn[9], Sn[9];
#pragma unroll
    for (int n = 2; n <= 8; ++n) {
        float t1 = 1.f - ab * qp[n - 1];
        float t2 = 1.f - cd * qp[n - 1];
        float t3 = 1.f - abcd * qp[2 * n - 2];
        float t4 = 1.f - abcd * qp[2 * n - 1];
        float t5 = 1.f - abcd * qp[2 * n];
        An[n] = (t1 * t2 * t3) / (t4 * t5);
        Cn[n] = ((1.f - qp[n]) * t1 * t2 * t3) / (t3 * t4);
        Sn[n] = 1.f / (1.f - qp[n]);
    }

    const float4* x4 = (const float4*)(x + (size_t)b * I_DIM + i0);
    float4 v0 = x4[0], v1 = x4[1];
    float xv[8] = {v0.x, v0.y, v0.z, v0.w, v1.x, v1.y, v1.z, v1.w};

    u16 ob[64];
#pragma unroll
    for (int j = 0; j < 8; ++j) {
        float xj = xv[j];
        float p1 = c1x * xj + c1c;
        ob[j * 8 + 0] = f2bf(p1);
        float pm2 = 1.f, pm1 = p1;
#pragma unroll
        for (int n = 2; n <= 8; ++n) {
            float pn = ((2.f * xj - An[n]) * pm1 - Cn[n] * pm2) * Sn[n];
            ob[j * 8 + n - 1] = f2bf(pn);
            pm2 = pm1; pm1 = pn;
        }
    }

    uint4* dst = (uint4*)(A + (size_t)rb * K_DIM + (size_t)i0 * 8);
    const uint4* s = (const uint4*)ob;
#pragma unroll
    for (int u = 0; u < 8; ++u) dst[u] = s[u];
}

// ---------------------------------------------------------------------------
// Kernel 3: phase-split deep-pipelined GEMM (m201-style).
// BM=256 x BN=128, BK=64, 512 thr (8 waves 4Mx2N, 64x64/wave).
// Triple-buffered LDS (144 KiB). Per K-tile: 2 phases x {8 ds_read_b128 +
// 3 gload_lds + barrier + MFMA*16 in setprio(1)} ; counted vmcnt(6) once per
// tile (T3+T4+T5), XOR swizzle via pre-swizzled source (T2), XCD swizzle (T1).
// ---------------------------------------------------------------------------
__global__ __launch_bounds__(512) void aw_gemm(
    const u16* __restrict__ A,
    const u16* __restrict__ B,
    const float* __restrict__ bias,
    float* __restrict__ C,
    int row0, int rowBlocks)
{
    __shared__ u16 As[3 * A_TILE];   // 96 KB
    __shared__ u16 Bs[3 * B_TILE];   // 48 KB

    int nwg = rowBlocks * 8;
    int bid = blockIdx.x;
    int per = nwg >> 3;
    int logical = (bid & 7) * per + (bid >> 3);
    int rowBlk = logical >> 3;       // 8 col-blocks
    int colBlk = logical & 7;

    const int tid  = threadIdx.x;
    const int lane = tid & 63;
    const int wid  = tid >> 6;
    const int wr = wid & 3;          // 4 M-waves
    const int wc = wid >> 2;         // 2 N-waves

    // --- per-thread constant staging addresses (k0 added per tile) ---
    const u16* gA[4]; const u16* gB[2];
    int ldsA[4], ldsB[2];
#pragma unroll
    for (int j = 0; j < 4; ++j) {
        int idx = j * 512 + tid;
        int r = idx >> 3, sl = idx & 7;
        gA[j] = A + (size_t)rowBlk * BM * K_DIM + (size_t)r * K_DIM + ((sl ^ (r & 7)) << 3);
        ldsA[j] = idx << 3;
    }
#pragma unroll
    for (int j = 0; j < 2; ++j) {
        int idx = j * 512 + tid;
        int r = idx >> 3, sl = idx & 7;
        gB[j] = B + (size_t)colBlk * BN * K_DIM + (size_t)r * K_DIM + ((sl ^ (r & 7)) << 3);
        ldsB[j] = idx << 3;
    }

    // --- per-thread constant fragment byte-offsets (XOR-swizzled reads) ---
    int offA[2][4], offB[2][4];
#pragma unroll
    for (int ks = 0; ks < 2; ++ks) {
#pragma unroll
        for (int mi = 0; mi < 4; ++mi) {
            int r = wr * 64 + mi * 16 + (lane & 15);
            int s = ks * 4 + (lane >> 4);
            offA[ks][mi] = r * 128 + ((s ^ (r & 7)) << 4);
        }
#pragma unroll
        for (int ni = 0; ni < 4; ++ni) {
            int r = wc * 64 + ni * 16 + (lane & 15);
            int s = ks * 4 + (lane >> 4);
            offB[ks][ni] = r * 128 + ((s ^ (r & 7)) << 4);
        }
    }

    f32x4 acc[4][4];
#pragma unroll
    for (int mi = 0; mi < 4; ++mi)
#pragma unroll
        for (int ni = 0; ni < 4; ++ni)
            acc[mi][ni] = (f32x4){0.f, 0.f, 0.f, 0.f};

    auto stageHalf = [&](int kt, int buf, int half) {
        const int k0 = kt * BK;
        u16* dA = As + buf * A_TILE;
        u16* dB = Bs + buf * B_TILE;
        if (half == 0) {
            gload_lds16(gA[0] + k0, dA + ldsA[0]);
            gload_lds16(gA[1] + k0, dA + ldsA[1]);
            gload_lds16(gB[0] + k0, dB + ldsB[0]);
        } else {
            gload_lds16(gA[2] + k0, dA + ldsA[2]);
            gload_lds16(gA[3] + k0, dA + ldsA[3]);
            gload_lds16(gB[1] + k0, dB + ldsB[1]);
        }
    };

    // prologue: 2 tiles in flight (12 loads)
    stageHalf(0, 0, 0); stageHalf(0, 0, 1);
    stageHalf(1, 1, 0); stageHalf(1, 1, 1);
    asm volatile("s_waitcnt vmcnt(6)" ::: "memory");   // tile 0 landed
    __builtin_amdgcn_s_barrier();

    int buf = 0;
    for (int t = 0; t < NT; ++t) {
        const char* aB = (const char*)(As + buf * A_TILE);
        const char* bB = (const char*)(Bs + buf * B_TILE);
        int nb = buf + 2; if (nb >= 3) nb -= 3;
        const bool pf = (t + 2 < NT);

        // ---- phase A (ks = 0): reads + half-stage || MFMA cluster ----
        bf16x8 a0[4], b0[4];
#pragma unroll
        for (int mi = 0; mi < 4; ++mi) a0[mi] = *(const bf16x8*)(aB + offA[0][mi]);
#pragma unroll
        for (int ni = 0; ni < 4; ++ni) b0[ni] = *(const bf16x8*)(bB + offB[0][ni]);
        if (pf) stageHalf(t + 2, nb, 0);
        __builtin_amdgcn_s_barrier();
        __builtin_amdgcn_s_setprio(1);
#pragma unroll
        for (int mi = 0; mi < 4; ++mi)
#pragma unroll
            for (int ni = 0; ni < 4; ++ni)
                acc[mi][ni] = __builtin_amdgcn_mfma_f32_16x16x32_bf16(
                    a0[mi], b0[ni], acc[mi][ni], 0, 0, 0);
        __builtin_amdgcn_s_setprio(0);
        __builtin_amdgcn_s_barrier();

        // ---- phase B (ks = 1) ----
        bf16x8 a1[4], b1[4];
#pragma unroll
        for (int mi = 0; mi < 4; ++mi) a1[mi] = *(const bf16x8*)(aB + offA[1][mi]);
#pragma unroll
        for (int ni = 0; ni < 4; ++ni) b1[ni] = *(const bf16x8*)(bB + offB[1][ni]);
        if (pf) stageHalf(t + 2, nb, 1);
        __builtin_amdgcn_s_barrier();
        __builtin_amdgcn_s_setprio(1);
#pragma unroll
        for (int mi = 0; mi < 4; ++mi)
#pragma unroll
            for (int ni = 0; ni < 4; ++ni)
                acc[mi][ni] = __builtin_amdgcn_mfma_f32_16x16x32_bf16(
                    a1[mi], b1[ni], acc[mi][ni], 0, 0, 0);
        __builtin_amdgcn_s_setprio(0);
        // counted drain, once per K-tile: tile t+1 must be resident before
        // next iteration's phase-A reads. Outstanding <= 12 here; vmcnt(6)
        // retires the oldest 6 = stage(t+1). Tail peels 6 -> 0.
        if (pf) { asm volatile("s_waitcnt vmcnt(6)" ::: "memory"); }
        else if (t + 1 < NT) { asm volatile("s_waitcnt vmcnt(0)" ::: "memory"); }
        __builtin_amdgcn_s_barrier();

        buf += 1; if (buf >= 3) buf -= 3;
    }

    // epilogue: D layout col=lane&15, row=(lane>>4)*4+j  [m89]
    int gRow = row0 + rowBlk * BM + wr * 64;
    int gCol = colBlk * BN + wc * 64;
#pragma unroll
    for (int mi = 0; mi < 4; ++mi) {
#pragma unroll
        for (int ni = 0; ni < 4; ++ni) {
            int rr = gRow + mi * 16 + ((lane >> 4) << 2);
            int cc = gCol + ni * 16 + (lane & 15);
            float bv = bias[cc];
            float* dst = C + (size_t)rr * N_DIM + cc;
#pragma unroll
            for (int j = 0; j < 4; ++j) dst[(size_t)j * N_DIM] = acc[mi][ni][j] + bv;
        }
    }
}

// ---------------------------------------------------------------------------
extern "C" void kernel_launch(void* const* d_in, const int* in_sizes, int n_in,
                              void* d_out, int out_size, void* d_ws, size_t ws_size,
                              hipStream_t stream)
{
    const float* x      = (const float*)d_in[0];
    const float* pa     = (const float*)d_in[1];
    const float* pb     = (const float*)d_in[2];
    const float* pc     = (const float*)d_in[3];
    const float* pd     = (const float*)d_in[4];
    const float* pq     = (const float*)d_in[5];
    const float* coeffs = (const float*)d_in[6];
    float* out = (float*)d_out;

    float* bias = (float*)d_ws;
    const size_t biasBytes = 4096;
    u16* Bt = (u16*)((char*)d_ws + biasBytes);
    const size_t btBytes = (size_t)N_DIM * K_DIM * sizeof(u16);   // 16.8 MB
    u16* Abuf = (u16*)((char*)d_ws + biasBytes + btBytes);
    size_t used = biasBytes + btBytes;
    size_t avail = ws_size > used ? ws_size - used : 0;

    int chunk = M_DIM;
    while (chunk > 256 && (size_t)chunk * K_DIM * sizeof(u16) > avail) chunk >>= 1;

    hipMemsetAsync(bias, 0, N_DIM * sizeof(float), stream);
    aw_transform<<<1024, 256, 0, stream>>>(coeffs, Bt, bias);

    for (int row0 = 0; row0 < M_DIM; row0 += chunk) {
        aw_basis<<<(chunk * 128) / 256, 256, 0, stream>>>(x, pa, pb, pc, pd, pq, Abuf, row0);
        int rowBlocks = chunk / BM;
        aw_gemm<<<rowBlocks * 8, 512, 0, stream>>>(Abuf, Bt, bias, out, row0, rowBlocks);
    }
}